// Round 4
// baseline (83.444 us; speedup 1.0000x reference)
//
#include <hip/hip_runtime.h>

#define B      64
#define C      128
#define H      56
#define HW     3136      // 56*56
#define HW4    784       // HW/4
#define NCHUNK 8
#define CPC    16        // C / NCHUNK
#define NEG_INF (-3.402823466e38f)

// ---------------- wave-local peak rounds (verified absmax=0 in R3) ----------
template<int TYPE>
__device__ void rounds_body(const float* __restrict__ S,
                            const int* __restrict__ scale,
                            float* __restrict__ out, int b) {
    constexpr int K    = (TYPE == 0) ? 3 : 2;
    constexpr int Hs   = H - K + 1;              // 54 / 55
    constexpr int n    = Hs * Hs;                // 2916 / 3025
    constexpr int half = (TYPE == 0) ? 112 : 56;
    constexpr int NJ   = (n + 63) / 64;          // 46 / 48

    const int lane = threadIdx.x & 63;

    // pooled map cached in registers, interleaved: cell idx = lane + 64*j
    float av[NJ];
    #pragma unroll
    for (int j = 0; j < NJ; ++j) {
        int i = lane + 64 * j;
        if (i < n) {
            int r = i / Hs, c = i - (i / Hs) * Hs;     // constexpr Hs -> magic mul
            float s = 0.f;
            #pragma unroll
            for (int dr = 0; dr < K; ++dr)
                #pragma unroll
                for (int dc = 0; dc < K; ++dc)
                    s += S[(r + dr) * H + (c + dc)];
            av[j] = s / (float)(K * K);
        } else {
            av[j] = NEG_INF;
        }
    }

    for (int p = 0; p < 3; ++p) {
        // lane-local argmax (ascending idx + strict '>' keeps first occurrence)
        float bv = NEG_INF; int bi = 0x7fffffff;
        #pragma unroll
        for (int j = 0; j < NJ; ++j) {
            int i = lane + 64 * j;
            if (av[j] > bv) { bv = av[j]; bi = i; }
        }
        // 64-lane butterfly, tie-break min linear index
        #pragma unroll
        for (int d = 1; d < 64; d <<= 1) {
            float ov = __shfl_xor(bv, d);
            int   oi = __shfl_xor(bi, d);
            if (ov > bv || (ov == bv && oi < bi)) { bv = ov; bi = oi; }
        }
        const float vmax = bv;
        const int   idx  = bi;

        if (lane == 0) {
            int lr = idx / Hs, lc = idx - (idx / Hs) * Hs;
            int pg = TYPE * 3 + p;
            out[1536 + (b * 6 + pg) * 2 + 0] = (float)lr;
            out[1536 + (b * 6 + pg) * 2 + 1] = (float)lc;
            out[2304 + b * 6 + pg] = vmax;

            int s0 = scale[b * 2 + 0], s1 = scale[b * 2 + 1];
            int smin = s0 < s1 ? s0 : s1;
            int sb0 = (s0 - smin) >> 1, sb1 = (s1 - smin) >> 1;
            float rate_h = (float)(2 * lr + H - Hs + 1) / (2.0f * H);
            float rate_w = (float)(2 * lc + H - Hs + 1) / (2.0f * H);
            int c0 = (int)__fadd_rn((float)sb0, __fmul_rn((float)smin, rate_h));
            int c1 = (int)__fadd_rn((float)sb1, __fmul_rn((float)smin, rate_w));
            int top = c0 - half, bot = c0 + half;
            int lef = c1 - half, rig = c1 + half;
            int bel0 = top < 0 ? top : 0, bel1 = lef < 0 ? lef : 0;
            top -= bel0; bot -= bel0; lef -= bel1; rig -= bel1;
            int ov0 = (bot - s0 > 0) ? (bot - s0) : 0;
            int ov1 = (rig - s1 > 0) ? (rig - s1) : 0;
            top = (top - ov0 > 0) ? (top - ov0) : 0;
            lef = (lef - ov1 > 0) ? (lef - ov1) : 0;
            bot -= ov0; rig -= ov1;
            float* il = out + (size_t)(b * 6 + pg) * 4;
            il[0] = (float)top; il[1] = (float)lef;
            il[2] = (float)bot; il[3] = (float)rig;
        }

        // erase: every cell == vmax gets its (clipped) 3x3 box zeroed
        if (p < 2) {
            #pragma unroll
            for (int j = 0; j < NJ; ++j) {
                unsigned long long m = __ballot(av[j] == vmax);
                while (m) {
                    int hl = __ffsll(m) - 1;
                    m &= m - 1;
                    int hidx = hl + 64 * j;
                    int hr = hidx / Hs, hc = hidx - (hidx / Hs) * Hs;
                    #pragma unroll
                    for (int jj = 0; jj < NJ; ++jj) {
                        int i = lane + 64 * jj;
                        int r = i / Hs, c = i - (i / Hs) * Hs;
                        bool inbox = (i < n) & (r >= hr - 1) & (r <= hr + 1)
                                             & (c >= hc - 1) & (c <= hc + 1);
                        if (inbox) av[jj] = 0.f;
                    }
                }
            }
        }
    }
}

// ---------------- fused kernel: chansum + last-block reduce + rounds --------
// grid = B*NCHUNK = 512 blocks, 256 threads. Each block sums 16 channels of
// one batch into part[b][chunk]; the 8th-arriving block per batch (atomic
// ticket) reduces the 8 partials into LDS S and runs both types' rounds.
__global__ __launch_bounds__(256) void fused_kernel(const float4* __restrict__ fm,
                                                    float4* __restrict__ part,
                                                    unsigned* __restrict__ cnt,
                                                    const int* __restrict__ scale,
                                                    float* __restrict__ out) {
    __shared__ float Smem[HW];
    __shared__ int   sm_last;

    const int b     = blockIdx.x >> 3;       // / NCHUNK
    const int chunk = blockIdx.x & 7;
    const int tid   = threadIdx.x;

    // Phase A: 16-channel partial sum, coalesced float4 streaming
    {
        const float4* base = fm + ((size_t)b * C + (size_t)chunk * CPC) * HW4;
        float4* dst = part + ((size_t)b * NCHUNK + chunk) * HW4;
        for (int i = tid; i < HW4; i += 256) {
            float x = 0.f, y = 0.f, z = 0.f, w = 0.f;
            #pragma unroll
            for (int c = 0; c < CPC; ++c) {
                float4 v = base[(size_t)c * HW4 + i];
                x += v.x; y += v.y; z += v.z; w += v.w;
            }
            dst[i] = make_float4(x, y, z, w);
        }
    }
    __syncthreads();                          // block's partial fully written

    // ticket: last block per batch proceeds (release-fence before, acquire after)
    if (tid == 0) {
        __threadfence();                      // release partial writes (device scope)
        unsigned old = atomicAdd(&cnt[b], 1u);
        sm_last = (old == NCHUNK - 1);
        if (sm_last) __threadfence();         // acquire other blocks' writes
    }
    __syncthreads();
    if (!sm_last) return;

    // Phase B: reduce 8 partials (L2/L3-warm) into S
    {
        float4* S4 = reinterpret_cast<float4*>(Smem);
        const float4* pb = part + (size_t)b * NCHUNK * HW4;
        for (int i = tid; i < HW4; i += 256) {
            float x = 0.f, y = 0.f, z = 0.f, w = 0.f;
            #pragma unroll
            for (int ch = 0; ch < NCHUNK; ++ch) {
                float4 v = pb[ch * HW4 + i];
                x += v.x; y += v.y; z += v.z; w += v.w;
            }
            S4[i] = make_float4(x, y, z, w);
        }
    }
    __syncthreads();

    // Phase C: wave 0 -> type 0, wave 1 -> type 1 (zero further barriers)
    const int wave = tid >> 6;
    if (wave == 0)      rounds_body<0>(Smem, scale, out, b);
    else if (wave == 1) rounds_body<1>(Smem, scale, out, b);
}

extern "C" void kernel_launch(void* const* d_in, const int* in_sizes, int n_in,
                              void* d_out, int out_size, void* d_ws, size_t ws_size,
                              hipStream_t stream) {
    const float* fm    = (const float*)d_in[0];
    const int*   scale = (const int*)d_in[1];
    float*       out   = (float*)d_out;

    unsigned* cnt  = (unsigned*)d_ws;                 // 64 counters (256 B)
    float*    part = (float*)((char*)d_ws + 4096);    // 6.4 MB partials

    hipMemsetAsync(cnt, 0, B * sizeof(unsigned), stream);
    hipLaunchKernelGGL(fused_kernel, dim3(B * NCHUNK), dim3(256), 0, stream,
                       (const float4*)fm, (float4*)part, cnt, scale, out);
}

// Round 5
// 47.497 us; speedup vs baseline: 1.7568x; 1.7568x over previous
//
#include <hip/hip_runtime.h>

#define B   64
#define C   128
#define H   56
#define HW  3136      // 56*56
#define HW4 784       // HW/4
#define NF4 (B * HW4) // 50176 float4 S-elements total
#define NEG_INF (-3.402823466e38f)

// ---------------- Kernel 1: direct channel sum -----------------
// grid = 196 blocks x 256 threads: one float4 pixel-group per thread, summed
// over all 128 channels (independent coalesced loads), written straight to S.
__global__ __launch_bounds__(256) void chansum_kernel(const float4* __restrict__ fm,
                                                      float4* __restrict__ S4) {
    int flat = blockIdx.x * 256 + threadIdx.x;     // 0..50175
    int b = flat / HW4;
    int g = flat - b * HW4;
    const float4* base = fm + (size_t)b * C * HW4 + g;
    float x = 0.f, y = 0.f, z = 0.f, w = 0.f;
    #pragma unroll 8
    for (int c = 0; c < C; ++c) {
        float4 v = base[(size_t)c * HW4];
        x += v.x; y += v.y; z += v.z; w += v.w;
    }
    S4[flat] = make_float4(x, y, z, w);
}

// ---------------- wave-local peak rounds (verified absmax=0 in R3) ----------
template<int TYPE>
__device__ void rounds_body(const float* __restrict__ S,
                            const int* __restrict__ scale,
                            float* __restrict__ out, int b) {
    constexpr int K    = (TYPE == 0) ? 3 : 2;
    constexpr int Hs   = H - K + 1;              // 54 / 55
    constexpr int n    = Hs * Hs;                // 2916 / 3025
    constexpr int half = (TYPE == 0) ? 112 : 56;
    constexpr int NJ   = (n + 63) / 64;          // 46 / 48

    const int lane = threadIdx.x & 63;

    // pooled map cached in registers, interleaved: cell idx = lane + 64*j
    float av[NJ];
    #pragma unroll
    for (int j = 0; j < NJ; ++j) {
        int i = lane + 64 * j;
        if (i < n) {
            int r = i / Hs, c = i - (i / Hs) * Hs;     // constexpr Hs -> magic mul
            float s = 0.f;
            #pragma unroll
            for (int dr = 0; dr < K; ++dr)
                #pragma unroll
                for (int dc = 0; dc < K; ++dc)
                    s += S[(r + dr) * H + (c + dc)];
            av[j] = s / (float)(K * K);
        } else {
            av[j] = NEG_INF;
        }
    }

    for (int p = 0; p < 3; ++p) {
        // lane-local argmax (ascending idx + strict '>' keeps first occurrence)
        float bv = NEG_INF; int bi = 0x7fffffff;
        #pragma unroll
        for (int j = 0; j < NJ; ++j) {
            int i = lane + 64 * j;
            if (av[j] > bv) { bv = av[j]; bi = i; }
        }
        // 64-lane butterfly, tie-break min linear index
        #pragma unroll
        for (int d = 1; d < 64; d <<= 1) {
            float ov = __shfl_xor(bv, d);
            int   oi = __shfl_xor(bi, d);
            if (ov > bv || (ov == bv && oi < bi)) { bv = ov; bi = oi; }
        }
        const float vmax = bv;
        const int   idx  = bi;

        if (lane == 0) {
            int lr = idx / Hs, lc = idx - (idx / Hs) * Hs;
            int pg = TYPE * 3 + p;
            out[1536 + (b * 6 + pg) * 2 + 0] = (float)lr;
            out[1536 + (b * 6 + pg) * 2 + 1] = (float)lc;
            out[2304 + b * 6 + pg] = vmax;

            int s0 = scale[b * 2 + 0], s1 = scale[b * 2 + 1];
            int smin = s0 < s1 ? s0 : s1;
            int sb0 = (s0 - smin) >> 1, sb1 = (s1 - smin) >> 1;
            float rate_h = (float)(2 * lr + H - Hs + 1) / (2.0f * H);
            float rate_w = (float)(2 * lc + H - Hs + 1) / (2.0f * H);
            int c0 = (int)__fadd_rn((float)sb0, __fmul_rn((float)smin, rate_h));
            int c1 = (int)__fadd_rn((float)sb1, __fmul_rn((float)smin, rate_w));
            int top = c0 - half, bot = c0 + half;
            int lef = c1 - half, rig = c1 + half;
            int bel0 = top < 0 ? top : 0, bel1 = lef < 0 ? lef : 0;
            top -= bel0; bot -= bel0; lef -= bel1; rig -= bel1;
            int ov0 = (bot - s0 > 0) ? (bot - s0) : 0;
            int ov1 = (rig - s1 > 0) ? (rig - s1) : 0;
            top = (top - ov0 > 0) ? (top - ov0) : 0;
            lef = (lef - ov1 > 0) ? (lef - ov1) : 0;
            bot -= ov0; rig -= ov1;
            float* il = out + (size_t)(b * 6 + pg) * 4;
            il[0] = (float)top; il[1] = (float)lef;
            il[2] = (float)bot; il[3] = (float)rig;
        }

        // erase: every cell == vmax gets its (clipped) 3x3 box zeroed
        if (p < 2) {
            #pragma unroll
            for (int j = 0; j < NJ; ++j) {
                unsigned long long m = __ballot(av[j] == vmax);
                while (m) {
                    int hl = __ffsll(m) - 1;
                    m &= m - 1;
                    int hidx = hl + 64 * j;
                    int hr = hidx / Hs, hc = hidx - (hidx / Hs) * Hs;
                    #pragma unroll
                    for (int jj = 0; jj < NJ; ++jj) {
                        int i = lane + 64 * jj;
                        int r = i / Hs, c = i - (i / Hs) * Hs;
                        bool inbox = (i < n) & (r >= hr - 1) & (r <= hr + 1)
                                             & (c >= hc - 1) & (c <= hc + 1);
                        if (inbox) av[jj] = 0.f;
                    }
                }
            }
        }
    }
}

// ---------------- Kernel 2: S -> LDS, wave-local rounds ----------------
// grid = 64 (one block per batch), 512 threads, one barrier. Reads only
// 12.5 KB/block of L2/L3-warm S.
__global__ __launch_bounds__(512) void peaks_kernel(const float4* __restrict__ S4g,
                                                    const int* __restrict__ scale,
                                                    float* __restrict__ out) {
    __shared__ float S[HW];
    const int b   = blockIdx.x;
    const int tid = threadIdx.x;

    float4* S4 = reinterpret_cast<float4*>(S);
    const float4* src = S4g + (size_t)b * HW4;
    #pragma unroll
    for (int i = tid; i < HW4; i += 512)
        S4[i] = src[i];
    __syncthreads();   // the only barrier

    const int wave = tid >> 6;
    if (wave == 0)      rounds_body<0>(S, scale, out, b);
    else if (wave == 1) rounds_body<1>(S, scale, out, b);
    // waves 2..7 retire
}

extern "C" void kernel_launch(void* const* d_in, const int* in_sizes, int n_in,
                              void* d_out, int out_size, void* d_ws, size_t ws_size,
                              hipStream_t stream) {
    const float* fm    = (const float*)d_in[0];
    const int*   scale = (const int*)d_in[1];
    float*       out   = (float*)d_out;
    float*       Sbuf  = (float*)d_ws;    // 800 KB channel-sum map

    hipLaunchKernelGGL(chansum_kernel, dim3(NF4 / 256), dim3(256), 0, stream,
                       (const float4*)fm, (float4*)Sbuf);
    hipLaunchKernelGGL(peaks_kernel, dim3(B), dim3(512), 0, stream,
                       (const float4*)Sbuf, scale, out);
}